// Round 1
// 950.744 us; speedup vs baseline: 1.0100x; 1.0100x over previous
//
#include <hip/hip_runtime.h>
#include <math.h>

#define LOG_2PI_F 1.8378770664093453f

// Native clang vector type: __builtin_nontemporal_load works on it directly
// (HIP's float4 struct does not always lower through the builtin).
typedef float v4f __attribute__((ext_vector_type(4)));

// Kernel 1: per-block partial sums of (o-x)^2.
// 2048 blocks x 256 threads = 32 waves/CU on 256 CUs, grid-stride loop.
// 2x unrolled with independent accumulators so two (o,x) float4 load pairs
// are in flight per iteration; nontemporal hints since this is a pure
// 1 GB stream with zero reuse (and the harness ws-poison thrashes L2/LLC
// between iterations anyway).
__global__ void __launch_bounds__(256)
sqdiff_partial(const v4f* __restrict__ o4, const v4f* __restrict__ x4,
               long long n4, long long n_total, const float* __restrict__ o_s,
               const float* __restrict__ x_s, float* __restrict__ partials) {
    long long idx = (long long)blockIdx.x * blockDim.x + threadIdx.x;
    long long stride = (long long)gridDim.x * blockDim.x;

    float acc0 = 0.f, acc1 = 0.f;
    long long i = idx;
    // main loop: two independent load pairs in flight per trip
    for (; i + stride < n4; i += 2 * stride) {
        v4f a0 = __builtin_nontemporal_load(o4 + i);
        v4f b0 = __builtin_nontemporal_load(x4 + i);
        v4f a1 = __builtin_nontemporal_load(o4 + i + stride);
        v4f b1 = __builtin_nontemporal_load(x4 + i + stride);
        v4f d0 = a0 - b0;
        v4f d1 = a1 - b1;
        acc0 += d0.x * d0.x + d0.y * d0.y + d0.z * d0.z + d0.w * d0.w;
        acc1 += d1.x * d1.x + d1.y * d1.y + d1.z * d1.z + d1.w * d1.w;
    }
    // remainder trip (if (n4/stride) is odd)
    for (; i < n4; i += stride) {
        v4f a = __builtin_nontemporal_load(o4 + i);
        v4f b = __builtin_nontemporal_load(x4 + i);
        v4f d = a - b;
        acc0 += d.x * d.x + d.y * d.y + d.z * d.z + d.w * d.w;
    }
    float acc = acc0 + acc1;

    // scalar tail (n_total not divisible by 4) -- first thread only
    if (idx == 0) {
        for (long long t = n4 * 4; t < n_total; ++t) {
            float d = o_s[t] - x_s[t];
            acc += d * d;
        }
    }

    // wave-64 butterfly-free down-reduction
    #pragma unroll
    for (int off = 32; off > 0; off >>= 1)
        acc += __shfl_down(acc, off, 64);
    __shared__ float lds[4];
    int wave = threadIdx.x >> 6;
    int lane = threadIdx.x & 63;
    if (lane == 0) lds[wave] = acc;
    __syncthreads();
    if (threadIdx.x == 0) {
        partials[blockIdx.x] = lds[0] + lds[1] + lds[2] + lds[3];
    }
}

// Kernel 2: reduce the 2048 block partials, apply log-likelihood epilogue.
__global__ void __launch_bounds__(256)
finalize(const float* __restrict__ partials, int np,
         const float* __restrict__ noise_p, float* __restrict__ out,
         float nd) {
    float acc = 0.f;
    for (int i = threadIdx.x; i < np; i += blockDim.x) acc += partials[i];
    #pragma unroll
    for (int off = 32; off > 0; off >>= 1)
        acc += __shfl_down(acc, off, 64);
    __shared__ float lds[4];
    int wave = threadIdx.x >> 6;
    int lane = threadIdx.x & 63;
    if (lane == 0) lds[wave] = acc;
    __syncthreads();
    if (threadIdx.x == 0) {
        float sq = lds[0] + lds[1] + lds[2] + lds[3];
        float noise = noise_p[0];
        out[0] = -0.5f * nd * LOG_2PI_F
               - 0.5f * nd * noise
               - 0.5f * expf(-2.f * noise) * sq;
    }
}

extern "C" void kernel_launch(void* const* d_in, const int* in_sizes, int n_in,
                              void* d_out, int out_size, void* d_ws, size_t ws_size,
                              hipStream_t stream) {
    const float* o = (const float*)d_in[0];
    const float* x = (const float*)d_in[1];
    const float* noise = (const float*)d_in[2];
    float* out = (float*)d_out;
    float* partials = (float*)d_ws;

    long long n = (long long)in_sizes[0];  // total elements = n_rows * d
    long long n4 = n >> 2;

    const int BLOCKS = 2048;   // 8 blocks/CU -> 32 waves/CU
    const int THREADS = 256;

    sqdiff_partial<<<BLOCKS, THREADS, 0, stream>>>(
        (const v4f*)o, (const v4f*)x, n4, n, o, x, partials);
    finalize<<<1, THREADS, 0, stream>>>(partials, BLOCKS, noise, out, (float)n);
}